// Round 7
// baseline (470.011 us; speedup 1.0000x reference)
//
#include <hip/hip_runtime.h>
#include <stdint.h>

#define N_NODES 1024
#define NCLS 10
#define KDIM 131072  // 1024*128

typedef unsigned short u16;
typedef __bf16 bf16x8 __attribute__((ext_vector_type(8)));
typedef float f32x4 __attribute__((ext_vector_type(4)));
typedef float f32x2 __attribute__((ext_vector_type(2)));

__device__ __forceinline__ float b2f_lo(uint32_t u) {
  union { float f; uint32_t u; } v; v.u = u << 16; return v.f;
}
__device__ __forceinline__ float b2f_hi(uint32_t u) {
  union { float f; uint32_t u; } v; v.u = u & 0xFFFF0000u; return v.f;
}
__device__ __forceinline__ u16 f2b(float f) {
  union { float f; uint32_t u; } v; v.f = f;
  uint32_t r = v.u + 0x7FFF + ((v.u >> 16) & 1);
  return (u16)(r >> 16);
}
__device__ __forceinline__ uint32_t pkbf(float a, float b) {
#if __has_builtin(__builtin_amdgcn_cvt_pk_bf16_f32)
  typedef __bf16 bf2 __attribute__((ext_vector_type(2)));
  bf2 r = __builtin_amdgcn_cvt_pk_bf16_f32(a, b);
  union { bf2 v; uint32_t u; } c; c.v = r; return c.u;
#else
  union { float f; uint32_t u; } va, vb; va.f = a; vb.f = b;
  uint32_t ra = (va.u + 0x7FFF + ((va.u >> 16) & 1)) >> 16;
  uint32_t rb = (vb.u + 0x7FFF + ((vb.u >> 16) & 1)) & 0xFFFF0000u;
  return ra | rb;
#endif
}
__device__ __forceinline__ uint32_t pkbf2(f32x2 z) { return pkbf(z.x, z.y); }

__device__ __forceinline__ void async_copy16(const u16* g, u16* l) {
  __builtin_amdgcn_global_load_lds(
      (const __attribute__((address_space(1))) void*)g,
      (__attribute__((address_space(3))) void*)l, 16, 0, 0);
}

// packed: accumulate 8 bf16 (one uint4) scaled by c into f32x2 acc[4] (v_pk_fma_f32)
__device__ __forceinline__ void agg8p(uint4 v, float c, f32x2* acc) {
  const uint32_t* u = (const uint32_t*)&v;
  f32x2 cv = {c, c};
#pragma unroll
  for (int e = 0; e < 4; e++) {
    f32x2 p = {b2f_lo(u[e]), b2f_hi(u[e])};
    acc[e] += p * cv;
  }
}

// ---------------- prep kernels ----------------
__global__ __launch_bounds__(256) void cvt_w_kernel(const float* __restrict__ w,
                                                    u16* __restrict__ o, int n) {
  int i = blockIdx.x * 256 + threadIdx.x;
  if (i < n) o[i] = f2b(w[i]);
}

__global__ __launch_bounds__(256) void prep_wc_kernel(const float* __restrict__ wc,
                                                      u16* __restrict__ o) {
  int i = blockIdx.x * 256 + threadIdx.x;  // 16*KDIM total
  int row = i >> 17;
  int col = i & (KDIM - 1);
  o[i] = (row < NCLS) ? f2b(wc[row * KDIM + col]) : (u16)0;
}

__global__ __launch_bounds__(256) void prep_tab_kernel(const float* __restrict__ adj,
                                                       int* __restrict__ nbi,
                                                       float* __restrict__ nbc,
                                                       float* __restrict__ r) {
  int m = blockIdx.x * 256 + threadIdx.x;
  if (m >= N_NODES) return;
  int i = m >> 5, j = m & 31;
  const float* arow = adj + (size_t)m * N_NODES;
  int n[5]; float c[5];
  n[0] = m;                      c[0] = arow[m];
  n[1] = (i > 0)  ? m - 32 : m;  c[1] = (i > 0)  ? arow[m - 32] : 0.f;
  n[2] = (i < 31) ? m + 32 : m;  c[2] = (i < 31) ? arow[m + 32] : 0.f;
  n[3] = (j > 0)  ? m - 1  : m;  c[3] = (j > 0)  ? arow[m - 1]  : 0.f;
  n[4] = (j < 31) ? m + 1  : m;  c[4] = (j < 31) ? arow[m + 1]  : 0.f;
  float s = 0.f;
#pragma unroll
  for (int t = 0; t < 5; t++) { nbi[m * 5 + t] = n[t]; nbc[m * 5 + t] = c[t]; s += c[t]; }
  r[m] = s;
}

__global__ __launch_bounds__(256) void outinit_kernel(const float* __restrict__ bc,
                                                      float* __restrict__ out) {
  int idx = blockIdx.x * 256 + threadIdx.x;
  if (idx < 256 * NCLS) out[idx] = bc[idx % NCLS];
}

// ---------------- fused layer1 + agg: g2 = A * relu((A x)W1^T + r.b1) ----------------
__global__ __launch_bounds__(256) void l1agg_kernel(
    const float* __restrict__ x,    // [chunk,3,1024]
    const float* __restrict__ W1,   // [256,3]
    const float* __restrict__ b1,   // [256]
    const int* __restrict__ nbi, const float* __restrict__ nbc,
    const float* __restrict__ r,    // [1024]
    u16* __restrict__ g)            // [chunk*1024, 256] = A.h1
{
  __shared__ u16 h1s[128 * 256];    // 64 KB
  __shared__ float gxs[128][4];
  __shared__ float W1s[768];
  __shared__ float b1s[256];
  int p0 = blockIdx.x * 64;
  int b = p0 >> 10;
  int m0 = p0 & 1023;
  int e0 = m0 - 32;
  int tid = threadIdx.x;

  b1s[tid] = b1[tid];
  for (int i = tid; i < 768; i += 256) W1s[i] = W1[i];

  if (tid < 128) {
    int n = e0 + tid;
    float g0 = 0.f, g1 = 0.f, g2 = 0.f, rn = 0.f;
    if (n >= 0 && n < N_NODES) {
      const float* xb = x + (size_t)b * 3072;
#pragma unroll
      for (int t = 0; t < 5; t++) {
        int nb = nbi[n * 5 + t]; float cf = nbc[n * 5 + t];
        g0 += cf * xb[nb];
        g1 += cf * xb[1024 + nb];
        g2 += cf * xb[2048 + nb];
      }
      rn = r[n];
    }
    gxs[tid][0] = g0; gxs[tid][1] = g1; gxs[tid][2] = g2; gxs[tid][3] = rn;
  }
  __syncthreads();

  int ch8 = (tid & 31) * 8;
  f32x2 wp[3][4], bp[4];
#pragma unroll
  for (int p = 0; p < 4; p++) {
    int c = ch8 + 2 * p;
    wp[0][p] = (f32x2){W1s[c * 3],     W1s[(c + 1) * 3]};
    wp[1][p] = (f32x2){W1s[c * 3 + 1], W1s[(c + 1) * 3 + 1]};
    wp[2][p] = (f32x2){W1s[c * 3 + 2], W1s[(c + 1) * 3 + 2]};
    bp[p]    = (f32x2){b1s[c],         b1s[c + 1]};
  }

#pragma unroll
  for (int it = 0; it < 16; it++) {
    int node = (tid >> 5) + it * 8;
    f32x2 g0v = {gxs[node][0], gxs[node][0]};
    f32x2 g1v = {gxs[node][1], gxs[node][1]};
    f32x2 g2v = {gxs[node][2], gxs[node][2]};
    f32x2 rnv = {gxs[node][3], gxs[node][3]};
    uint32_t pk[4];
#pragma unroll
    for (int p = 0; p < 4; p++) {
      f32x2 z = g0v * wp[0][p] + g1v * wp[1][p] + g2v * wp[2][p] + rnv * bp[p];
      z.x = fmaxf(z.x, 0.f); z.y = fmaxf(z.y, 0.f);
      pk[p] = pkbf2(z);
    }
    *(uint4*)&h1s[node * 256 + ch8] = *(uint4*)pk;
  }
  __syncthreads();

#pragma unroll
  for (int it = 0; it < 8; it++) {
    int node = (tid >> 5) + it * 8;
    int m = m0 + node;
    f32x2 acc[4] = {};
#pragma unroll
    for (int t = 0; t < 5; t++) {
      int nb = nbi[m * 5 + t]; float cf = nbc[m * 5 + t];
      agg8p(*(const uint4*)&h1s[(nb - e0) * 256 + ch8], cf, acc);
    }
    uint4 o;
    o.x = pkbf2(acc[0]); o.y = pkbf2(acc[1]);
    o.z = pkbf2(acc[2]); o.w = pkbf2(acc[3]);
    *(uint4*)&g[(size_t)(p0 + node) * 256 + ch8] = o;
  }
}

// ---------------- mm2: C = relu(A W^T + r.bias), K=256 ----------------
// Full B-tile (128x256 = 64 KB) staged ONCE via glds (XOR-swizzled octets).
// Single barrier; K-loop is barrier-free: A streams global->VGPR with a
// depth-3 rotating prefetch (compiler emits fine-grained vmcnt, no drains).
__global__ __launch_bounds__(256) void mm_kernel(
    const u16* __restrict__ A, const u16* __restrict__ W,
    const float* __restrict__ bias, const float* __restrict__ r,
    u16* __restrict__ C, int N)
{
  const int K = 256;
  __shared__ u16 Bs[128 * 256];   // 64 KB
  int n0 = blockIdx.x * 128;
  int m0 = blockIdx.y * 128;
  int tid = threadIdx.x;
  int w = tid >> 6, l = tid & 63;
  int wm = w >> 1, wn = w & 1;

  // stage B: wave w -> rows w*32..w*32+31; phys octet p holds logical octet p^(row&7)
  {
    int r2 = l >> 5, poct = l & 31;
#pragma unroll
    for (int q = 0; q < 16; q++) {
      int row = w * 32 + q * 2 + r2;
      int loct = poct ^ (row & 7);
      async_copy16(W + (size_t)(n0 + row) * K + loct * 8, &Bs[(w * 32 + q * 2) * 256]);
    }
  }

  int lrow = l & 15, lq = l >> 4;
  const u16* pa = A + (size_t)(m0 + wm * 64 + lrow) * K + lq * 8;

  // depth-3 A prefetch (rotating, statically indexed under full unroll)
  uint4 ab[3][4];
#pragma unroll
  for (int d = 0; d < 3; d++)
#pragma unroll
    for (int t = 0; t < 4; t++)
      ab[d][t] = *(const uint4*)(pa + (size_t)t * 16 * K + d * 32);

  f32x4 acc[4][4] = {};
  const u16* pb = &Bs[(wn * 64 + lrow) * 256];
  int sw = lrow & 7;
  __syncthreads();

#pragma unroll
  for (int kq = 0; kq < 8; kq++) {
    bf16x8 af[4], bf[4];
#pragma unroll
    for (int t = 0; t < 4; t++) {
      union { uint4 u; bf16x8 b; } cv; cv.u = ab[kq % 3][t];
      af[t] = cv.b;
      bf[t] = *(const bf16x8*)(pb + t * 16 * 256 + ((kq * 4 + lq) ^ sw) * 8);
    }
    if (kq < 5) {
#pragma unroll
      for (int t = 0; t < 4; t++)
        ab[kq % 3][t] = *(const uint4*)(pa + (size_t)t * 16 * K + (kq + 3) * 32);
    }
#pragma unroll
    for (int mt = 0; mt < 4; mt++)
#pragma unroll
      for (int nt = 0; nt < 4; nt++)
        acc[mt][nt] = __builtin_amdgcn_mfma_f32_16x16x32_bf16(af[mt], bf[nt], acc[mt][nt], 0, 0, 0);
  }

#pragma unroll
  for (int mt = 0; mt < 4; mt++)
#pragma unroll
    for (int nt = 0; nt < 4; nt++) {
      f32x4 v = acc[mt][nt];
      int col = n0 + wn * 64 + nt * 16 + lrow;
      float bs = bias[col];
#pragma unroll
      for (int i2 = 0; i2 < 4; i2++) {
        int row = m0 + wm * 64 + mt * 16 + lq * 4 + i2;
        float val = v[i2] + r[row & 1023] * bs;
        C[(size_t)row * N + col] = f2b(fmaxf(val, 0.f));
      }
    }
}

// ---------------- mm3agg: h3 = relu((A h2) W3^T + r.b3) ----------------
// Same barrier-free skeleton: full W3 (64 KB) in LDS, A-frags aggregated in
// registers (5 nbr uint4 + packed FMA per frag; h2 rows L1/L2-hot).
__global__ __launch_bounds__(256) void mm3agg_kernel(
    const u16* __restrict__ H,      // h2 [chunk*1024, 256]
    const u16* __restrict__ W,      // W3b [128, 256]
    const float* __restrict__ bias, const float* __restrict__ r,
    const int* __restrict__ nbi, const float* __restrict__ nbc,
    u16* __restrict__ C)            // h3 [chunk*1024, 128]
{
  const int K = 256, N = 128;
  __shared__ u16 Bs[128 * 256];   // 64 KB
  int m0 = blockIdx.x * 128;
  int tid = threadIdx.x;
  int w = tid >> 6, l = tid & 63;
  int wm = w >> 1, wn = w & 1;

  {
    int r2 = l >> 5, poct = l & 31;
#pragma unroll
    for (int q = 0; q < 16; q++) {
      int row = w * 32 + q * 2 + r2;
      int loct = poct ^ (row & 7);
      async_copy16(W + (size_t)row * K + loct * 8, &Bs[(w * 32 + q * 2) * 256]);
    }
  }

  int lrow = l & 15, lq = l >> 4;
  const u16* hb = H + ((size_t)(m0 >> 10) << 10) * 256 + lq * 8;  // image base + k-offset
  int offs[4][5]; float cf[4][5];
#pragma unroll
  for (int t = 0; t < 4; t++) {
    int node = (m0 & 1023) + wm * 64 + t * 16 + lrow;
#pragma unroll
    for (int j = 0; j < 5; j++) {
      offs[t][j] = nbi[node * 5 + j] * 256;
      cf[t][j] = nbc[node * 5 + j];
    }
  }

  f32x4 acc[4][4] = {};
  const u16* pb = &Bs[(wn * 64 + lrow) * 256];
  int sw = lrow & 7;
  __syncthreads();

#pragma unroll
  for (int kq = 0; kq < 8; kq++) {
    bf16x8 af[4], bf[4];
#pragma unroll
    for (int t = 0; t < 4; t++) {
      uint4 Lv[5];
#pragma unroll
      for (int j = 0; j < 5; j++)
        Lv[j] = *(const uint4*)(hb + offs[t][j] + kq * 32);
      f32x2 a2[4] = {};
#pragma unroll
      for (int j = 0; j < 5; j++) agg8p(Lv[j], cf[t][j], a2);
      union { uint32_t u[4]; bf16x8 b; } cv;
      cv.u[0] = pkbf2(a2[0]); cv.u[1] = pkbf2(a2[1]);
      cv.u[2] = pkbf2(a2[2]); cv.u[3] = pkbf2(a2[3]);
      af[t] = cv.b;
      bf[t] = *(const bf16x8*)(pb + t * 16 * 256 + ((kq * 4 + lq) ^ sw) * 8);
    }
#pragma unroll
    for (int mt = 0; mt < 4; mt++)
#pragma unroll
      for (int nt = 0; nt < 4; nt++)
        acc[mt][nt] = __builtin_amdgcn_mfma_f32_16x16x32_bf16(af[mt], bf[nt], acc[mt][nt], 0, 0, 0);
  }

#pragma unroll
  for (int mt = 0; mt < 4; mt++)
#pragma unroll
    for (int nt = 0; nt < 4; nt++) {
      f32x4 v = acc[mt][nt];
      int col = wn * 64 + nt * 16 + lrow;
      float bs = bias[col];
#pragma unroll
      for (int i2 = 0; i2 < 4; i2++) {
        int row = m0 + wm * 64 + mt * 16 + lq * 4 + i2;
        float val = v[i2] + r[row & 1023] * bs;
        C[(size_t)row * N + col] = f2b(fmaxf(val, 0.f));
      }
    }
}

// ---------------- classifier ----------------
__global__ __launch_bounds__(256) void cls_kernel(
    const u16* __restrict__ h3,   // [chunk, KDIM] bf16
    const u16* __restrict__ Wcb,  // [16, KDIM] bf16 (rows 10..15 zero)
    float* __restrict__ out,      // [256, 10]
    int b0)
{
  int mt = blockIdx.x;
  int split = blockIdx.y;
  int w = threadIdx.x >> 6, l = threadIdx.x & 63;
  int lrow = l & 15, lq = l >> 4;
  f32x4 acc = {};
  int kbase = split * 4096 + w * 1024;
  const u16* pa = h3 + (size_t)(mt * 16 + lrow) * KDIM + kbase + lq * 8;
  const u16* pb = Wcb + (size_t)lrow * KDIM + kbase + lq * 8;
#pragma unroll 4
  for (int kk = 0; kk < 1024; kk += 32) {
    bf16x8 a = *(const bf16x8*)(pa + kk);
    bf16x8 b = *(const bf16x8*)(pb + kk);
    acc = __builtin_amdgcn_mfma_f32_16x16x32_bf16(a, b, acc, 0, 0, 0);
  }
  if (lrow < NCLS) {
#pragma unroll
    for (int i2 = 0; i2 < 4; i2++) {
      int b = b0 + mt * 16 + lq * 4 + i2;
      atomicAdd(&out[b * NCLS + lrow], acc[i2]);
    }
  }
}

extern "C" void kernel_launch(void* const* d_in, const int* in_sizes, int n_in,
                              void* d_out, int out_size, void* d_ws, size_t ws_size,
                              hipStream_t stream) {
  const float* x   = (const float*)d_in[0];
  const float* W1  = (const float*)d_in[1];
  const float* b1  = (const float*)d_in[2];
  const float* W2  = (const float*)d_in[3];
  const float* b2  = (const float*)d_in[4];
  const float* W3  = (const float*)d_in[5];
  const float* b3  = (const float*)d_in[6];
  const float* Wc  = (const float*)d_in[7];
  const float* bc  = (const float*)d_in[8];
  const float* adj = (const float*)d_in[9];
  float* out = (float*)d_out;
  const int B = 256;

  uint8_t* ws = (uint8_t*)d_ws;
  u16* W2b = (u16*)ws;  ws += (size_t)256 * 256 * 2;
  u16* W3b = (u16*)ws;  ws += (size_t)128 * 256 * 2;
  u16* Wcb = (u16*)ws;  ws += (size_t)16 * KDIM * 2;
  float* rr  = (float*)ws; ws += 1024 * 4;
  int*   nbi = (int*)ws;   ws += 1024 * 5 * 4;
  float* nbc = (float*)ws; ws += 1024 * 5 * 4;
  uintptr_t al = ((uintptr_t)ws + 255) & ~(uintptr_t)255;
  ws = (uint8_t*)al;
  size_t used = (size_t)(ws - (uint8_t*)d_ws);
  size_t avail = (ws_size > used) ? ws_size - used : 0;
  int chunk = 256;
  while (chunk > 32 && (size_t)chunk * 1024 * 256 * 2 * 2 > avail) chunk >>= 1;
  u16* bufA = (u16*)ws;
  u16* bufB = bufA + (size_t)chunk * 1024 * 256;

  cvt_w_kernel<<<256, 256, 0, stream>>>(W2, W2b, 256 * 256);
  cvt_w_kernel<<<128, 256, 0, stream>>>(W3, W3b, 128 * 256);
  prep_wc_kernel<<<(16 * KDIM) / 256, 256, 0, stream>>>(Wc, Wcb);
  prep_tab_kernel<<<4, 256, 0, stream>>>(adj, nbi, nbc, rr);
  outinit_kernel<<<(256 * NCLS + 255) / 256, 256, 0, stream>>>(bc, out);

  for (int b0 = 0; b0 < B; b0 += chunk) {
    const float* xb = x + (size_t)b0 * 3 * 1024;
    int M = chunk * 1024;
    // g2 = A.h1  -> bufB
    l1agg_kernel<<<M / 64, 256, 0, stream>>>(xb, W1, b1, nbi, nbc, rr, bufB);
    // h2 = relu(g2 W2^T + r.b2) -> bufA
    {
      dim3 g(2, M / 128);
      mm_kernel<<<g, 256, 0, stream>>>(bufB, W2b, b2, rr, bufA, 256);
    }
    // h3 = relu((A.h2) W3^T + r.b3) -> bufB
    mm3agg_kernel<<<M / 128, 256, 0, stream>>>(bufA, W3b, b3, rr, nbi, nbc, bufB);
    dim3 gc(chunk / 16, 32);
    cls_kernel<<<gc, 256, 0, stream>>>(bufB, Wcb, out, b0);
  }
}

// Round 8
// 433.768 us; speedup vs baseline: 1.0836x; 1.0836x over previous
//
#include <hip/hip_runtime.h>
#include <stdint.h>

#define N_NODES 1024
#define NCLS 10
#define KDIM 131072  // 1024*128

typedef unsigned short u16;
typedef __bf16 bf16x8 __attribute__((ext_vector_type(8)));
typedef float f32x4 __attribute__((ext_vector_type(4)));
typedef float f32x2 __attribute__((ext_vector_type(2)));

__device__ __forceinline__ float b2f_lo(uint32_t u) {
  union { float f; uint32_t u; } v; v.u = u << 16; return v.f;
}
__device__ __forceinline__ float b2f_hi(uint32_t u) {
  union { float f; uint32_t u; } v; v.u = u & 0xFFFF0000u; return v.f;
}
__device__ __forceinline__ u16 f2b(float f) {
  union { float f; uint32_t u; } v; v.f = f;
  uint32_t r = v.u + 0x7FFF + ((v.u >> 16) & 1);
  return (u16)(r >> 16);
}
__device__ __forceinline__ uint32_t pkbf(float a, float b) {
#if __has_builtin(__builtin_amdgcn_cvt_pk_bf16_f32)
  typedef __bf16 bf2 __attribute__((ext_vector_type(2)));
  bf2 r = __builtin_amdgcn_cvt_pk_bf16_f32(a, b);
  union { bf2 v; uint32_t u; } c; c.v = r; return c.u;
#else
  union { float f; uint32_t u; } va, vb; va.f = a; vb.f = b;
  uint32_t ra = (va.u + 0x7FFF + ((va.u >> 16) & 1)) >> 16;
  uint32_t rb = (vb.u + 0x7FFF + ((vb.u >> 16) & 1)) & 0xFFFF0000u;
  return ra | rb;
#endif
}
__device__ __forceinline__ uint32_t pkbf2(f32x2 z) { return pkbf(z.x, z.y); }

__device__ __forceinline__ void async_copy16(const u16* g, u16* l) {
  __builtin_amdgcn_global_load_lds(
      (const __attribute__((address_space(1))) void*)g,
      (__attribute__((address_space(3))) void*)l, 16, 0, 0);
}

// packed: accumulate 8 bf16 (one uint4) scaled by c into f32x2 acc[4] (v_pk_fma_f32)
__device__ __forceinline__ void agg8p(uint4 v, float c, f32x2* acc) {
  const uint32_t* u = (const uint32_t*)&v;
  f32x2 cv = {c, c};
#pragma unroll
  for (int e = 0; e < 4; e++) {
    f32x2 p = {b2f_lo(u[e]), b2f_hi(u[e])};
    acc[e] += p * cv;
  }
}

// ---------------- prep kernels ----------------
__global__ __launch_bounds__(256) void cvt_w_kernel(const float* __restrict__ w,
                                                    u16* __restrict__ o, int n) {
  int i = blockIdx.x * 256 + threadIdx.x;
  if (i < n) o[i] = f2b(w[i]);
}

// WcT[k][16] bf16 (cls-major transposed, rows 10..15 zero), k = node*128+col
__global__ __launch_bounds__(256) void prep_wct_kernel(const float* __restrict__ wc,
                                                       u16* __restrict__ o) {
  int i = blockIdx.x * 256 + threadIdx.x;   // 131072*16 total
  int k = i >> 4;
  int c = i & 15;
  o[i] = (c < NCLS) ? f2b(wc[(size_t)c * KDIM + k]) : (u16)0;
}

__global__ __launch_bounds__(256) void prep_tab_kernel(const float* __restrict__ adj,
                                                       int* __restrict__ nbi,
                                                       float* __restrict__ nbc,
                                                       float* __restrict__ r) {
  int m = blockIdx.x * 256 + threadIdx.x;
  if (m >= N_NODES) return;
  int i = m >> 5, j = m & 31;
  const float* arow = adj + (size_t)m * N_NODES;
  int n[5]; float c[5];
  n[0] = m;                      c[0] = arow[m];
  n[1] = (i > 0)  ? m - 32 : m;  c[1] = (i > 0)  ? arow[m - 32] : 0.f;
  n[2] = (i < 31) ? m + 32 : m;  c[2] = (i < 31) ? arow[m + 32] : 0.f;
  n[3] = (j > 0)  ? m - 1  : m;  c[3] = (j > 0)  ? arow[m - 1]  : 0.f;
  n[4] = (j < 31) ? m + 1  : m;  c[4] = (j < 31) ? arow[m + 1]  : 0.f;
  float s = 0.f;
#pragma unroll
  for (int t = 0; t < 5; t++) { nbi[m * 5 + t] = n[t]; nbc[m * 5 + t] = c[t]; s += c[t]; }
  r[m] = s;
}

__global__ __launch_bounds__(256) void outinit_kernel(const float* __restrict__ bc,
                                                      float* __restrict__ out) {
  int idx = blockIdx.x * 256 + threadIdx.x;
  if (idx < 256 * NCLS) out[idx] = bc[idx % NCLS];
}

// ---------------- fused layer1 + agg: g2 = A * relu((A x)W1^T + r.b1) ----------------
__global__ __launch_bounds__(256) void l1agg_kernel(
    const float* __restrict__ x,    // [chunk,3,1024]
    const float* __restrict__ W1,   // [256,3]
    const float* __restrict__ b1,   // [256]
    const int* __restrict__ nbi, const float* __restrict__ nbc,
    const float* __restrict__ r,    // [1024]
    u16* __restrict__ g)            // [chunk*1024, 256] = A.h1
{
  __shared__ u16 h1s[128 * 256];    // 64 KB
  __shared__ float gxs[128][4];
  __shared__ float W1s[768];
  __shared__ float b1s[256];
  int p0 = blockIdx.x * 64;
  int b = p0 >> 10;
  int m0 = p0 & 1023;
  int e0 = m0 - 32;
  int tid = threadIdx.x;

  b1s[tid] = b1[tid];
  for (int i = tid; i < 768; i += 256) W1s[i] = W1[i];

  if (tid < 128) {
    int n = e0 + tid;
    float g0 = 0.f, g1 = 0.f, g2 = 0.f, rn = 0.f;
    if (n >= 0 && n < N_NODES) {
      const float* xb = x + (size_t)b * 3072;
#pragma unroll
      for (int t = 0; t < 5; t++) {
        int nb = nbi[n * 5 + t]; float cf = nbc[n * 5 + t];
        g0 += cf * xb[nb];
        g1 += cf * xb[1024 + nb];
        g2 += cf * xb[2048 + nb];
      }
      rn = r[n];
    }
    gxs[tid][0] = g0; gxs[tid][1] = g1; gxs[tid][2] = g2; gxs[tid][3] = rn;
  }
  __syncthreads();

  int ch8 = (tid & 31) * 8;
  f32x2 wp[3][4], bp[4];
#pragma unroll
  for (int p = 0; p < 4; p++) {
    int c = ch8 + 2 * p;
    wp[0][p] = (f32x2){W1s[c * 3],     W1s[(c + 1) * 3]};
    wp[1][p] = (f32x2){W1s[c * 3 + 1], W1s[(c + 1) * 3 + 1]};
    wp[2][p] = (f32x2){W1s[c * 3 + 2], W1s[(c + 1) * 3 + 2]};
    bp[p]    = (f32x2){b1s[c],         b1s[c + 1]};
  }

#pragma unroll
  for (int it = 0; it < 16; it++) {
    int node = (tid >> 5) + it * 8;
    f32x2 g0v = {gxs[node][0], gxs[node][0]};
    f32x2 g1v = {gxs[node][1], gxs[node][1]};
    f32x2 g2v = {gxs[node][2], gxs[node][2]};
    f32x2 rnv = {gxs[node][3], gxs[node][3]};
    uint32_t pk[4];
#pragma unroll
    for (int p = 0; p < 4; p++) {
      f32x2 z = g0v * wp[0][p] + g1v * wp[1][p] + g2v * wp[2][p] + rnv * bp[p];
      z.x = fmaxf(z.x, 0.f); z.y = fmaxf(z.y, 0.f);
      pk[p] = pkbf2(z);
    }
    *(uint4*)&h1s[node * 256 + ch8] = *(uint4*)pk;
  }
  __syncthreads();

#pragma unroll
  for (int it = 0; it < 8; it++) {
    int node = (tid >> 5) + it * 8;
    int m = m0 + node;
    f32x2 acc[4] = {};
#pragma unroll
    for (int t = 0; t < 5; t++) {
      int nb = nbi[m * 5 + t]; float cf = nbc[m * 5 + t];
      agg8p(*(const uint4*)&h1s[(nb - e0) * 256 + ch8], cf, acc);
    }
    uint4 o;
    o.x = pkbf2(acc[0]); o.y = pkbf2(acc[1]);
    o.z = pkbf2(acc[2]); o.w = pkbf2(acc[3]);
    *(uint4*)&g[(size_t)(p0 + node) * 256 + ch8] = o;
  }
}

// ---------------- mm2: C = relu(A W^T + r.bias), K=256 ----------------
// Tile 128m x 64n, BK=64 dbuf (48 KB LDS -> 3 blocks/CU), XOR-swizzled staging
// (r5-verified math), one barrier/iter, glds k+1 issued right after the barrier.
__global__ __launch_bounds__(256) void mm_kernel(
    const u16* __restrict__ A, const u16* __restrict__ W,
    const float* __restrict__ bias, const float* __restrict__ r,
    u16* __restrict__ C, int N)
{
  const int K = 256;
  __shared__ u16 As[2][128 * 64];   // 2x16 KB
  __shared__ u16 Bs[2][64 * 64];    // 2x8 KB
  int n0 = blockIdx.x * 64;
  int m0 = blockIdx.y * 128;
  int tid = threadIdx.x;
  int w = tid >> 6, l = tid & 63;

  int r8 = l >> 3, oct = l & 7;
  int so = (oct ^ r8) << 3;                 // swizzled k-offset (elements)
  const u16* ga0 = A + (size_t)(m0 + w * 32 + r8) * K + so;
  const u16* gb0 = W + (size_t)(n0 + w * 16 + r8) * K + so;

#define MM_ISSUE(kq, buf) \
  _Pragma("unroll") for (int q = 0; q < 4; q++) \
    async_copy16(ga0 + (size_t)q * 8 * K + (kq) * 64, &As[buf][(w * 32 + q * 8) * 64]); \
  _Pragma("unroll") for (int q = 0; q < 2; q++) \
    async_copy16(gb0 + (size_t)q * 8 * K + (kq) * 64, &Bs[buf][(w * 16 + q * 8) * 64]);

  MM_ISSUE(0, 0);

  f32x4 acc[2][4] = {};
  int lrow = l & 15, lq = l >> 4;
  int s = lrow & 7;

#pragma unroll
  for (int kq = 0; kq < 4; kq++) {
    int buf = kq & 1;
    __syncthreads();
    if (kq < 3) { MM_ISSUE(kq + 1, buf ^ 1); }
    const u16* pa = &As[buf][(w * 32 + lrow) * 64];
    const u16* pb = &Bs[buf][lrow * 64];
#pragma unroll
    for (int kh = 0; kh < 2; kh++) {
      int po = (((kh << 2) | lq) ^ s) << 3;
      bf16x8 af[2], bf[4];
#pragma unroll
      for (int t = 0; t < 2; t++) af[t] = *(const bf16x8*)(pa + t * 16 * 64 + po);
#pragma unroll
      for (int t = 0; t < 4; t++) bf[t] = *(const bf16x8*)(pb + t * 16 * 64 + po);
#pragma unroll
      for (int mt = 0; mt < 2; mt++)
#pragma unroll
        for (int nt = 0; nt < 4; nt++)
          acc[mt][nt] = __builtin_amdgcn_mfma_f32_16x16x32_bf16(af[mt], bf[nt], acc[mt][nt], 0, 0, 0);
    }
  }
#undef MM_ISSUE

#pragma unroll
  for (int mt = 0; mt < 2; mt++)
#pragma unroll
    for (int nt = 0; nt < 4; nt++) {
      f32x4 v = acc[mt][nt];
      int col = n0 + nt * 16 + lrow;
      float bs = bias[col];
#pragma unroll
      for (int i2 = 0; i2 < 4; i2++) {
        int row = m0 + w * 32 + mt * 16 + lq * 4 + i2;
        float val = v[i2] + r[row & 1023] * bs;
        C[(size_t)row * N + col] = f2b(fmaxf(val, 0.f));
      }
    }
}

// ---------------- mm3agg + cls: out[b] += relu((A h2) W3^T + r.b3) . WcT ----------------
// BK=32 dbuf pipelined (r6-verified coverage); A-chunk aggregated from register
// prefetch. All 128 rows of a block = ONE image -> classifier fused in epilogue:
// h3 never touches HBM. LDS 36 KB.
__global__ __launch_bounds__(256) void mm3agg_kernel(
    const u16* __restrict__ H,      // h2 [chunk*1024, 256]
    const u16* __restrict__ W,      // W3b [128, 256]
    const float* __restrict__ bias, const float* __restrict__ r,
    const int* __restrict__ nbi, const float* __restrict__ nbc,
    const u16* __restrict__ WcT,    // [131072][16] bf16
    float* __restrict__ out,        // [256,10]
    int b0)
{
  const int K = 256;
  const int AST = 40;               // padded A row stride (elements)
  __shared__ u16 As[2][128 * AST];  // 2x10 KB
  __shared__ u16 Bs[2][128 * 32];   // 2x8 KB
  int m0 = blockIdx.x * 128;
  int tid = threadIdx.x;
  int w = tid >> 6, l = tid & 63;
  int wm = w >> 1, wn = w & 1;

  // aggregation: thread -> (row = tid/2, 16-col half of each 32-k chunk)
  int arow = tid >> 1;
  int acol = (tid & 1) * 16;
  int pg = m0 + arow;
  int node0 = pg & 1023;
  const u16* hb = H + ((size_t)(pg >> 10) << 10) * 256 + acol;
  const u16* nbp[5]; float cf[5];
#pragma unroll
  for (int j = 0; j < 5; j++) {
    nbp[j] = hb + (size_t)nbi[node0 * 5 + j] * 256;
    cf[j] = nbc[node0 * 5 + j];
  }

  // B staging
  int srow = w * 16 + (l >> 2);
  int skoff = (l & 3) * 8;
  const u16* gb0 = W + (size_t)srow * K + skoff;

#define M3_ISSUEB(kq, buf) \
  _Pragma("unroll") for (int q = 0; q < 2; q++) \
    async_copy16(gb0 + (size_t)q * 64 * K + (kq) * 32, &Bs[buf][(q * 64 + w * 16) * 32]);

#define M3_LOADA(kq) \
  _Pragma("unroll") for (int j = 0; j < 5; j++) \
    _Pragma("unroll") for (int q = 0; q < 2; q++) \
      L[j][q] = *(const uint4*)(nbp[j] + (kq) * 32 + q * 8);

#define M3_AGGSTORE(buf) { \
  u16* dst = &As[buf][arow * AST + acol]; \
  _Pragma("unroll") for (int q = 0; q < 2; q++) { \
    f32x2 a2[4] = {}; \
    _Pragma("unroll") for (int j = 0; j < 5; j++) agg8p(L[j][q], cf[j], a2); \
    uint4 o; \
    o.x = pkbf2(a2[0]); o.y = pkbf2(a2[1]); \
    o.z = pkbf2(a2[2]); o.w = pkbf2(a2[3]); \
    *(uint4*)(dst + q * 8) = o; \
  } }

  uint4 L[5][2];
  M3_ISSUEB(0, 0);
  M3_LOADA(0);
  M3_AGGSTORE(0);

  f32x4 acc[4][4] = {};
  int lrow = l & 15, lq = l >> 4;

#pragma unroll
  for (int kq = 0; kq < 8; kq++) {
    int buf = kq & 1;
    __syncthreads();
    if (kq < 7) {
      M3_ISSUEB(kq + 1, buf ^ 1);
      M3_LOADA(kq + 1);               // in flight during MFMA below
    }
    const u16* pa = &As[buf][(wm * 64 + lrow) * AST + lq * 8];
    const u16* pb = &Bs[buf][(wn * 64 + lrow) * 32 + lq * 8];
    bf16x8 af[4], bf[4];
#pragma unroll
    for (int t = 0; t < 4; t++) {
      af[t] = *(const bf16x8*)(pa + t * 16 * AST);
      bf[t] = *(const bf16x8*)(pb + t * 16 * 32);
    }
#pragma unroll
    for (int mt = 0; mt < 4; mt++)
#pragma unroll
      for (int nt = 0; nt < 4; nt++)
        acc[mt][nt] = __builtin_amdgcn_mfma_f32_16x16x32_bf16(af[mt], bf[nt], acc[mt][nt], 0, 0, 0);
    if (kq < 7) M3_AGGSTORE(buf ^ 1);
  }
#undef M3_ISSUEB
#undef M3_LOADA
#undef M3_AGGSTORE

  // fused classifier epilogue: out[b, 0..9] += relu(h3) . WcT  (h3 never stored)
  f32x2 o5[5] = {};
#pragma unroll
  for (int mt = 0; mt < 4; mt++)
#pragma unroll
    for (int nt = 0; nt < 4; nt++) {
      f32x4 v = acc[mt][nt];
      int col = wn * 64 + nt * 16 + lrow;
      float bs = bias[col];
#pragma unroll
      for (int i2 = 0; i2 < 4; i2++) {
        int row = m0 + wm * 64 + mt * 16 + lq * 4 + i2;
        float val = fmaxf(v[i2] + r[row & 1023] * bs, 0.f);
        const u16* wt = WcT + ((size_t)((row & 1023) * 128 + col) << 4);
        uint4 wa = *(const uint4*)wt;
        uint32_t wb = *(const uint32_t*)(wt + 8);
        f32x2 vv = {val, val};
        o5[0] += vv * (f32x2){b2f_lo(wa.x), b2f_hi(wa.x)};
        o5[1] += vv * (f32x2){b2f_lo(wa.y), b2f_hi(wa.y)};
        o5[2] += vv * (f32x2){b2f_lo(wa.z), b2f_hi(wa.z)};
        o5[3] += vv * (f32x2){b2f_lo(wa.w), b2f_hi(wa.w)};
        o5[4] += vv * (f32x2){b2f_lo(wb),   b2f_hi(wb)};
      }
    }
  // wave reduction (all lanes end with the wave total)
#pragma unroll
  for (int off = 1; off < 64; off <<= 1) {
#pragma unroll
    for (int e = 0; e < 5; e++) {
      o5[e].x += __shfl_xor(o5[e].x, off);
      o5[e].y += __shfl_xor(o5[e].y, off);
    }
  }
  if (l == 0) {
    float* ob = out + (size_t)(b0 + (m0 >> 10)) * NCLS;
    atomicAdd(ob + 0, o5[0].x); atomicAdd(ob + 1, o5[0].y);
    atomicAdd(ob + 2, o5[1].x); atomicAdd(ob + 3, o5[1].y);
    atomicAdd(ob + 4, o5[2].x); atomicAdd(ob + 5, o5[2].y);
    atomicAdd(ob + 6, o5[3].x); atomicAdd(ob + 7, o5[3].y);
    atomicAdd(ob + 8, o5[4].x); atomicAdd(ob + 9, o5[4].y);
  }
}

extern "C" void kernel_launch(void* const* d_in, const int* in_sizes, int n_in,
                              void* d_out, int out_size, void* d_ws, size_t ws_size,
                              hipStream_t stream) {
  const float* x   = (const float*)d_in[0];
  const float* W1  = (const float*)d_in[1];
  const float* b1  = (const float*)d_in[2];
  const float* W2  = (const float*)d_in[3];
  const float* b2  = (const float*)d_in[4];
  const float* W3  = (const float*)d_in[5];
  const float* b3  = (const float*)d_in[6];
  const float* Wc  = (const float*)d_in[7];
  const float* bc  = (const float*)d_in[8];
  const float* adj = (const float*)d_in[9];
  float* out = (float*)d_out;
  const int B = 256;

  uint8_t* ws = (uint8_t*)d_ws;
  u16* W2b = (u16*)ws;  ws += (size_t)256 * 256 * 2;
  u16* W3b = (u16*)ws;  ws += (size_t)128 * 256 * 2;
  u16* WcT = (u16*)ws;  ws += (size_t)KDIM * 16 * 2;   // 4 MB transposed classifier
  float* rr  = (float*)ws; ws += 1024 * 4;
  int*   nbi = (int*)ws;   ws += 1024 * 5 * 4;
  float* nbc = (float*)ws; ws += 1024 * 5 * 4;
  uintptr_t al = ((uintptr_t)ws + 255) & ~(uintptr_t)255;
  ws = (uint8_t*)al;
  size_t used = (size_t)(ws - (uint8_t*)d_ws);
  size_t avail = (ws_size > used) ? ws_size - used : 0;
  int chunk = 256;
  while (chunk > 32 && (size_t)chunk * 1024 * 256 * 2 * 2 > avail) chunk >>= 1;
  u16* bufA = (u16*)ws;
  u16* bufB = bufA + (size_t)chunk * 1024 * 256;

  cvt_w_kernel<<<256, 256, 0, stream>>>(W2, W2b, 256 * 256);
  cvt_w_kernel<<<128, 256, 0, stream>>>(W3, W3b, 128 * 256);
  prep_wct_kernel<<<(KDIM * 16) / 256, 256, 0, stream>>>(Wc, WcT);
  prep_tab_kernel<<<4, 256, 0, stream>>>(adj, nbi, nbc, rr);
  outinit_kernel<<<(256 * NCLS + 255) / 256, 256, 0, stream>>>(bc, out);

  for (int b0 = 0; b0 < B; b0 += chunk) {
    const float* xb = x + (size_t)b0 * 3 * 1024;
    int M = chunk * 1024;
    // g2 = A.h1  -> bufB
    l1agg_kernel<<<M / 64, 256, 0, stream>>>(xb, W1, b1, nbi, nbc, rr, bufB);
    // h2 = relu(g2 W2^T + r.b2) -> bufA  (n-tile fastest: 4 adjacent blocks share A in L2)
    {
      dim3 g(4, M / 128);
      mm_kernel<<<g, 256, 0, stream>>>(bufB, W2b, b2, rr, bufA, 256);
    }
    // out += relu((A.h2) W3^T + r.b3) . Wc^T   (agg + GEMM + classifier fused)
    mm3agg_kernel<<<M / 128, 256, 0, stream>>>(bufA, W3b, b3, rr, nbi, nbc, WcT, out, b0);
  }
}

// Round 9
// 372.082 us; speedup vs baseline: 1.2632x; 1.1658x over previous
//
#include <hip/hip_runtime.h>
#include <stdint.h>

#define N_NODES 1024
#define NCLS 10
#define KDIM 131072  // 1024*128

typedef unsigned short u16;
typedef __bf16 bf16x8 __attribute__((ext_vector_type(8)));
typedef float f32x4 __attribute__((ext_vector_type(4)));
typedef float f32x2 __attribute__((ext_vector_type(2)));

__device__ __forceinline__ float b2f_lo(uint32_t u) {
  union { float f; uint32_t u; } v; v.u = u << 16; return v.f;
}
__device__ __forceinline__ float b2f_hi(uint32_t u) {
  union { float f; uint32_t u; } v; v.u = u & 0xFFFF0000u; return v.f;
}
__device__ __forceinline__ u16 f2b(float f) {
  union { float f; uint32_t u; } v; v.f = f;
  uint32_t r = v.u + 0x7FFF + ((v.u >> 16) & 1);
  return (u16)(r >> 16);
}
__device__ __forceinline__ uint32_t pkbf(float a, float b) {
#if __has_builtin(__builtin_amdgcn_cvt_pk_bf16_f32)
  typedef __bf16 bf2 __attribute__((ext_vector_type(2)));
  bf2 r = __builtin_amdgcn_cvt_pk_bf16_f32(a, b);
  union { bf2 v; uint32_t u; } c; c.v = r; return c.u;
#else
  union { float f; uint32_t u; } va, vb; va.f = a; vb.f = b;
  uint32_t ra = (va.u + 0x7FFF + ((va.u >> 16) & 1)) >> 16;
  uint32_t rb = (vb.u + 0x7FFF + ((vb.u >> 16) & 1)) & 0xFFFF0000u;
  return ra | rb;
#endif
}
__device__ __forceinline__ uint32_t pkbf2(f32x2 z) { return pkbf(z.x, z.y); }

__device__ __forceinline__ void async_copy16(const u16* g, u16* l) {
  __builtin_amdgcn_global_load_lds(
      (const __attribute__((address_space(1))) void*)g,
      (__attribute__((address_space(3))) void*)l, 16, 0, 0);
}

// packed: accumulate 8 bf16 (one uint4) scaled by c into f32x2 acc[4] (v_pk_fma_f32)
__device__ __forceinline__ void agg8p(uint4 v, float c, f32x2* acc) {
  const uint32_t* u = (const uint32_t*)&v;
  f32x2 cv = {c, c};
#pragma unroll
  for (int e = 0; e < 4; e++) {
    f32x2 p = {b2f_lo(u[e]), b2f_hi(u[e])};
    acc[e] += p * cv;
  }
}

// ---------------- prep kernels ----------------
// Pack W [N,256] fp32 into MFMA-B-fragment order:
// Wf[((nt*8 + kq)*64 + lane)*8 + j] = W[(nt*16 + (lane&15))*256 + kq*32 + (lane>>4)*8 + j]
__global__ __launch_bounds__(256) void prep_wfrag_kernel(const float* __restrict__ w,
                                                         u16* __restrict__ o, int n) {
  int i = blockIdx.x * 256 + threadIdx.x;
  if (i >= n) return;
  int j = i & 7;
  int l = (i >> 3) & 63;
  int kq = (i >> 9) & 7;
  int nt = i >> 12;
  o[i] = f2b(w[(nt * 16 + (l & 15)) * 256 + kq * 32 + (l >> 4) * 8 + j]);
}

// Wcb [16][KDIM] bf16, rows 10..15 zero
__global__ __launch_bounds__(256) void prep_wc_kernel(const float* __restrict__ wc,
                                                      u16* __restrict__ o) {
  int i = blockIdx.x * 256 + threadIdx.x;  // 16*KDIM total
  int row = i >> 17;
  int col = i & (KDIM - 1);
  o[i] = (row < NCLS) ? f2b(wc[row * KDIM + col]) : (u16)0;
}

__global__ __launch_bounds__(256) void prep_tab_kernel(const float* __restrict__ adj,
                                                       int* __restrict__ nbi,
                                                       float* __restrict__ nbc,
                                                       float* __restrict__ r) {
  int m = blockIdx.x * 256 + threadIdx.x;
  if (m >= N_NODES) return;
  int i = m >> 5, j = m & 31;
  const float* arow = adj + (size_t)m * N_NODES;
  int n[5]; float c[5];
  n[0] = m;                      c[0] = arow[m];
  n[1] = (i > 0)  ? m - 32 : m;  c[1] = (i > 0)  ? arow[m - 32] : 0.f;
  n[2] = (i < 31) ? m + 32 : m;  c[2] = (i < 31) ? arow[m + 32] : 0.f;
  n[3] = (j > 0)  ? m - 1  : m;  c[3] = (j > 0)  ? arow[m - 1]  : 0.f;
  n[4] = (j < 31) ? m + 1  : m;  c[4] = (j < 31) ? arow[m + 1]  : 0.f;
  float s = 0.f;
#pragma unroll
  for (int t = 0; t < 5; t++) { nbi[m * 5 + t] = n[t]; nbc[m * 5 + t] = c[t]; s += c[t]; }
  r[m] = s;
}

__global__ __launch_bounds__(256) void outinit_kernel(const float* __restrict__ bc,
                                                      float* __restrict__ out) {
  int idx = blockIdx.x * 256 + threadIdx.x;
  if (idx < 256 * NCLS) out[idx] = bc[idx % NCLS];
}

// ---------------- fused layer1 + agg: g2 = A * relu((A x)W1^T + r.b1) ----------------
__global__ __launch_bounds__(256) void l1agg_kernel(
    const float* __restrict__ x,    // [chunk,3,1024]
    const float* __restrict__ W1,   // [256,3]
    const float* __restrict__ b1,   // [256]
    const int* __restrict__ nbi, const float* __restrict__ nbc,
    const float* __restrict__ r,    // [1024]
    u16* __restrict__ g)            // [chunk*1024, 256] = A.h1
{
  __shared__ u16 h1s[128 * 256];    // 64 KB
  __shared__ float gxs[128][4];
  __shared__ float W1s[768];
  __shared__ float b1s[256];
  int p0 = blockIdx.x * 64;
  int b = p0 >> 10;
  int m0 = p0 & 1023;
  int e0 = m0 - 32;
  int tid = threadIdx.x;

  b1s[tid] = b1[tid];
  for (int i = tid; i < 768; i += 256) W1s[i] = W1[i];

  if (tid < 128) {
    int n = e0 + tid;
    float g0 = 0.f, g1 = 0.f, g2 = 0.f, rn = 0.f;
    if (n >= 0 && n < N_NODES) {
      const float* xb = x + (size_t)b * 3072;
#pragma unroll
      for (int t = 0; t < 5; t++) {
        int nb = nbi[n * 5 + t]; float cf = nbc[n * 5 + t];
        g0 += cf * xb[nb];
        g1 += cf * xb[1024 + nb];
        g2 += cf * xb[2048 + nb];
      }
      rn = r[n];
    }
    gxs[tid][0] = g0; gxs[tid][1] = g1; gxs[tid][2] = g2; gxs[tid][3] = rn;
  }
  __syncthreads();

  int ch8 = (tid & 31) * 8;
  f32x2 wp[3][4], bp[4];
#pragma unroll
  for (int p = 0; p < 4; p++) {
    int c = ch8 + 2 * p;
    wp[0][p] = (f32x2){W1s[c * 3],     W1s[(c + 1) * 3]};
    wp[1][p] = (f32x2){W1s[c * 3 + 1], W1s[(c + 1) * 3 + 1]};
    wp[2][p] = (f32x2){W1s[c * 3 + 2], W1s[(c + 1) * 3 + 2]};
    bp[p]    = (f32x2){b1s[c],         b1s[c + 1]};
  }

#pragma unroll
  for (int it = 0; it < 16; it++) {
    int node = (tid >> 5) + it * 8;
    f32x2 g0v = {gxs[node][0], gxs[node][0]};
    f32x2 g1v = {gxs[node][1], gxs[node][1]};
    f32x2 g2v = {gxs[node][2], gxs[node][2]};
    f32x2 rnv = {gxs[node][3], gxs[node][3]};
    uint32_t pk[4];
#pragma unroll
    for (int p = 0; p < 4; p++) {
      f32x2 z = g0v * wp[0][p] + g1v * wp[1][p] + g2v * wp[2][p] + rnv * bp[p];
      z.x = fmaxf(z.x, 0.f); z.y = fmaxf(z.y, 0.f);
      pk[p] = pkbf2(z);
    }
    *(uint4*)&h1s[node * 256 + ch8] = *(uint4*)pk;
  }
  __syncthreads();

#pragma unroll
  for (int it = 0; it < 8; it++) {
    int node = (tid >> 5) + it * 8;
    int m = m0 + node;
    f32x2 acc[4] = {};
#pragma unroll
    for (int t = 0; t < 5; t++) {
      int nb = nbi[m * 5 + t]; float cf = nbc[m * 5 + t];
      agg8p(*(const uint4*)&h1s[(nb - e0) * 256 + ch8], cf, acc);
    }
    uint4 o;
    o.x = pkbf2(acc[0]); o.y = pkbf2(acc[1]);
    o.z = pkbf2(acc[2]); o.w = pkbf2(acc[3]);
    *(uint4*)&g[(size_t)(p0 + node) * 256 + ch8] = o;
  }
}

// ---------------- mm2: C = relu(A W^T + r.bias), K=256 ----------------
// 128x128 tile, BK=64 A-only dbuf LDS (32 KB), one barrier/iter (drains A-glds
// only). B read directly from fragment-packed Wf in global (L2-hot, coalesced
// 1 KB/wave loads, compiler fine-grained vmcnt).
__global__ __launch_bounds__(256) void mm_kernel(
    const u16* __restrict__ A, const u16* __restrict__ Wf,
    const float* __restrict__ bias, const float* __restrict__ r,
    u16* __restrict__ C, int N)
{
  const int K = 256;
  __shared__ u16 As[2][128 * 64];   // 2x16 KB
  int n0 = blockIdx.x * 128;
  int m0 = blockIdx.y * 128;
  int tid = threadIdx.x;
  int w = tid >> 6, l = tid & 63;
  int wm = w >> 1, wn = w & 1;

  int r8 = l >> 3, oct = l & 7;
  int so = (oct ^ r8) << 3;                 // swizzled k-offset (elements)
  const u16* ga0 = A + (size_t)(m0 + w * 32 + r8) * K + so;

#define MM_ISSUE(kq, buf) \
  _Pragma("unroll") for (int q = 0; q < 4; q++) \
    async_copy16(ga0 + (size_t)q * 8 * K + (kq) * 64, &As[buf][(w * 32 + q * 8) * 64]);

  MM_ISSUE(0, 0);

  f32x4 acc[4][4] = {};
  int lrow = l & 15, lq = l >> 4;
  int s = lrow & 7;
  const u16* wfb = Wf + (((size_t)(n0 >> 4) + wn * 4) * 8) * 512 + l * 8;

#pragma unroll
  for (int kq = 0; kq < 4; kq++) {
    int buf = kq & 1;
    __syncthreads();
    if (kq < 3) { MM_ISSUE(kq + 1, buf ^ 1); }
    const u16* pa = &As[buf][(wm * 64 + lrow) * 64];
#pragma unroll
    for (int kh = 0; kh < 2; kh++) {
      int kk = kq * 2 + kh;                   // logical k-chunk of 32
      int po = (((kh << 2) | lq) ^ s) << 3;   // physical octet offset
      bf16x8 af[4], bf[4];
#pragma unroll
      for (int t = 0; t < 4; t++) {
        af[t] = *(const bf16x8*)(pa + t * 16 * 64 + po);
        bf[t] = *(const bf16x8*)(wfb + ((size_t)t * 8 + kk) * 512);
      }
#pragma unroll
      for (int mt = 0; mt < 4; mt++)
#pragma unroll
        for (int nt = 0; nt < 4; nt++)
          acc[mt][nt] = __builtin_amdgcn_mfma_f32_16x16x32_bf16(af[mt], bf[nt], acc[mt][nt], 0, 0, 0);
    }
  }
#undef MM_ISSUE

#pragma unroll
  for (int mt = 0; mt < 4; mt++)
#pragma unroll
    for (int nt = 0; nt < 4; nt++) {
      f32x4 v = acc[mt][nt];
      int col = n0 + wn * 64 + nt * 16 + lrow;
      float bs = bias[col];
#pragma unroll
      for (int i2 = 0; i2 < 4; i2++) {
        int row = m0 + wm * 64 + mt * 16 + lq * 4 + i2;
        float val = v[i2] + r[row & 1023] * bs;
        C[(size_t)row * N + col] = f2b(fmaxf(val, 0.f));
      }
    }
}

// ---------------- mm3agg: h3 = relu((A h2) W3^T + r.b3) ----------------
// BK=32 dbuf pipelined (r5 skeleton); A aggregated from register prefetch into
// padded LDS (20 KB total); B direct from fragment-packed W3f (L2-hot) -> the
// per-iter barrier drains lgkm only (no glds in flight for this kernel).
__global__ __launch_bounds__(256) void mm3agg_kernel(
    const u16* __restrict__ H,      // h2 [chunk*1024, 256]
    const u16* __restrict__ W3f,    // fragment-packed [8nt][8kq][64][8]
    const float* __restrict__ bias, const float* __restrict__ r,
    const int* __restrict__ nbi, const float* __restrict__ nbc,
    u16* __restrict__ C)            // h3 [chunk*1024, 128]
{
  const int AST = 40;               // padded A row stride (elements)
  __shared__ u16 As[2][128 * AST];  // 2x10 KB
  int m0 = blockIdx.x * 128;
  int tid = threadIdx.x;
  int w = tid >> 6, l = tid & 63;
  int wm = w >> 1, wn = w & 1;

  // aggregation: thread -> (row = tid/2, 16-col half of each 32-k chunk)
  int arow = tid >> 1;
  int acol = (tid & 1) * 16;
  int pg = m0 + arow;
  int node0 = pg & 1023;
  const u16* hb = H + ((size_t)(pg >> 10) << 10) * 256 + acol;
  const u16* nbp[5]; float cf[5];
#pragma unroll
  for (int j = 0; j < 5; j++) {
    nbp[j] = hb + (size_t)nbi[node0 * 5 + j] * 256;
    cf[j] = nbc[node0 * 5 + j];
  }

#define M3_LOADA(kq) \
  _Pragma("unroll") for (int j = 0; j < 5; j++) \
    _Pragma("unroll") for (int q = 0; q < 2; q++) \
      L[j][q] = *(const uint4*)(nbp[j] + (kq) * 32 + q * 8);

#define M3_AGGSTORE(buf) { \
  u16* dst = &As[buf][arow * AST + acol]; \
  _Pragma("unroll") for (int q = 0; q < 2; q++) { \
    f32x2 a2[4] = {}; \
    _Pragma("unroll") for (int j = 0; j < 5; j++) agg8p(L[j][q], cf[j], a2); \
    uint4 o; \
    o.x = pkbf2(a2[0]); o.y = pkbf2(a2[1]); \
    o.z = pkbf2(a2[2]); o.w = pkbf2(a2[3]); \
    *(uint4*)(dst + q * 8) = o; \
  } }

  uint4 L[5][2];
  M3_LOADA(0);
  M3_AGGSTORE(0);

  f32x4 acc[4][4] = {};
  int lrow = l & 15, lq = l >> 4;
  const u16* wfb = W3f + ((size_t)wn * 4 * 8) * 512 + l * 8;

#pragma unroll
  for (int kq = 0; kq < 8; kq++) {
    int buf = kq & 1;
    __syncthreads();
    if (kq < 7) M3_LOADA(kq + 1);   // in flight during MFMA below
    const u16* pa = &As[buf][(wm * 64 + lrow) * AST + lq * 8];
    bf16x8 af[4], bf[4];
#pragma unroll
    for (int t = 0; t < 4; t++) {
      af[t] = *(const bf16x8*)(pa + t * 16 * AST);
      bf[t] = *(const bf16x8*)(wfb + ((size_t)t * 8 + kq) * 512);
    }
#pragma unroll
    for (int mt = 0; mt < 4; mt++)
#pragma unroll
      for (int nt = 0; nt < 4; nt++)
        acc[mt][nt] = __builtin_amdgcn_mfma_f32_16x16x32_bf16(af[mt], bf[nt], acc[mt][nt], 0, 0, 0);
    if (kq < 7) M3_AGGSTORE(buf ^ 1);
  }
#undef M3_LOADA
#undef M3_AGGSTORE

#pragma unroll
  for (int mt = 0; mt < 4; mt++)
#pragma unroll
    for (int nt = 0; nt < 4; nt++) {
      f32x4 v = acc[mt][nt];
      int col = wn * 64 + nt * 16 + lrow;
      float bs = bias[col];
#pragma unroll
      for (int i2 = 0; i2 < 4; i2++) {
        int row = m0 + wm * 64 + mt * 16 + lq * 4 + i2;
        float val = v[i2] + r[row & 1023] * bs;
        C[(size_t)row * 128 + col] = f2b(fmaxf(val, 0.f));
      }
    }
}

// ---------------- classifier ----------------
__global__ __launch_bounds__(256) void cls_kernel(
    const u16* __restrict__ h3,   // [chunk, KDIM] bf16
    const u16* __restrict__ Wcb,  // [16, KDIM] bf16 (rows 10..15 zero)
    float* __restrict__ out,      // [256, 10]
    int b0)
{
  int mt = blockIdx.x;
  int split = blockIdx.y;
  int w = threadIdx.x >> 6, l = threadIdx.x & 63;
  int lrow = l & 15, lq = l >> 4;
  f32x4 acc = {};
  int kbase = split * 4096 + w * 1024;
  const u16* pa = h3 + (size_t)(mt * 16 + lrow) * KDIM + kbase + lq * 8;
  const u16* pb = Wcb + (size_t)lrow * KDIM + kbase + lq * 8;
#pragma unroll 4
  for (int kk = 0; kk < 1024; kk += 32) {
    bf16x8 a = *(const bf16x8*)(pa + kk);
    bf16x8 b = *(const bf16x8*)(pb + kk);
    acc = __builtin_amdgcn_mfma_f32_16x16x32_bf16(a, b, acc, 0, 0, 0);
  }
  if (lrow < NCLS) {
#pragma unroll
    for (int i2 = 0; i2 < 4; i2++) {
      int b = b0 + mt * 16 + lq * 4 + i2;
      atomicAdd(&out[b * NCLS + lrow], acc[i2]);
    }
  }
}

extern "C" void kernel_launch(void* const* d_in, const int* in_sizes, int n_in,
                              void* d_out, int out_size, void* d_ws, size_t ws_size,
                              hipStream_t stream) {
  const float* x   = (const float*)d_in[0];
  const float* W1  = (const float*)d_in[1];
  const float* b1  = (const float*)d_in[2];
  const float* W2  = (const float*)d_in[3];
  const float* b2  = (const float*)d_in[4];
  const float* W3  = (const float*)d_in[5];
  const float* b3  = (const float*)d_in[6];
  const float* Wc  = (const float*)d_in[7];
  const float* bc  = (const float*)d_in[8];
  const float* adj = (const float*)d_in[9];
  float* out = (float*)d_out;
  const int B = 256;

  uint8_t* ws = (uint8_t*)d_ws;
  u16* W2f = (u16*)ws;  ws += (size_t)256 * 256 * 2;   // frag-packed W2
  u16* W3f = (u16*)ws;  ws += (size_t)128 * 256 * 2;   // frag-packed W3
  u16* Wcb = (u16*)ws;  ws += (size_t)16 * KDIM * 2;
  float* rr  = (float*)ws; ws += 1024 * 4;
  int*   nbi = (int*)ws;   ws += 1024 * 5 * 4;
  float* nbc = (float*)ws; ws += 1024 * 5 * 4;
  uintptr_t al = ((uintptr_t)ws + 255) & ~(uintptr_t)255;
  ws = (uint8_t*)al;
  size_t used = (size_t)(ws - (uint8_t*)d_ws);
  size_t avail = (ws_size > used) ? ws_size - used : 0;
  int chunk = 256;
  while (chunk > 32 && (size_t)chunk * 1024 * 256 * 2 * 2 > avail) chunk >>= 1;
  u16* bufA = (u16*)ws;
  u16* bufB = bufA + (size_t)chunk * 1024 * 256;

  prep_wfrag_kernel<<<256, 256, 0, stream>>>(W2, W2f, 256 * 256);
  prep_wfrag_kernel<<<128, 256, 0, stream>>>(W3, W3f, 128 * 256);
  prep_wc_kernel<<<(16 * KDIM) / 256, 256, 0, stream>>>(Wc, Wcb);
  prep_tab_kernel<<<4, 256, 0, stream>>>(adj, nbi, nbc, rr);
  outinit_kernel<<<(256 * NCLS + 255) / 256, 256, 0, stream>>>(bc, out);

  for (int b0 = 0; b0 < B; b0 += chunk) {
    const float* xb = x + (size_t)b0 * 3 * 1024;
    int M = chunk * 1024;
    // g2 = A.h1  -> bufB
    l1agg_kernel<<<M / 64, 256, 0, stream>>>(xb, W1, b1, nbi, nbc, rr, bufB);
    // h2 = relu(g2 W2^T + r.b2) -> bufA  (n-tile fastest: 2 adjacent blocks share A in L2)
    {
      dim3 g(2, M / 128);
      mm_kernel<<<g, 256, 0, stream>>>(bufB, W2f, b2, rr, bufA, 256);
    }
    // h3 = relu((A.h2) W3^T + r.b3) -> bufB
    mm3agg_kernel<<<M / 128, 256, 0, stream>>>(bufA, W3f, b3, rr, nbi, nbc, bufB);
    // out += h3 . Wc^T
    dim3 gc(chunk / 16, 32);
    cls_kernel<<<gc, 256, 0, stream>>>(bufB, Wcb, out, b0);
  }
}